// Round 10
// baseline (155.101 us; speedup 1.0000x reference)
//
#include <hip/hip_runtime.h>

// GeoCyclicPadding: x (B=2, C=192, H=360, W=720) f32, p=3 -> out (B,C,366,726)
//
// R9 + 4x work per bulk thread (ILP):
//  BULK (24,300 blocks): thread handles float4 group k of rows r, r+90,
//    r+180, r+270 of plane bc -- 4 independent 16B-ALIGNED loads in flight,
//    4 stores (store side misaligned by 4/12B; R7 proved fixing it costs
//    more than it saves). Same-k row-strided quads keep every instruction
//    fully lane-coalesced. 64B/thread amortizes index math and wave setup.
//  EDGE (6,507 blocks, unchanged from R9): per plane EPP=4338 jobs:
//    q<2160: middle-row edge cols (scalar); else halo-row float2 groups.
//  Bresenham-interleaved so edge latency hides under the bulk BW stream.

typedef float f4a __attribute__((ext_vector_type(4), aligned(16)));
typedef float f4u __attribute__((ext_vector_type(4), aligned(4)));
typedef float f2u __attribute__((ext_vector_type(2), aligned(4)));

__global__ __launch_bounds__(256) void geo_pad_kernel(const float* __restrict__ x,
                                                      float* __restrict__ out) {
    constexpr int W = 720, H = 360, p = 3, Wp = 726, Hp = 366;
    constexpr unsigned EPP  = 2160u + 6u * 363u;   // 4338 edge jobs / plane
    constexpr unsigned EBLK = 384u * EPP / 256u;   // 6,507 edge blocks
    constexpr unsigned BBLK = 384u * 90u * 180u / 256u;  // 24,300 bulk blocks
    constexpr unsigned TBLK = BBLK + EBLK;         // 30,807

    const unsigned i = blockIdx.x;
    const unsigned long long iE = (unsigned long long)i * EBLK;
    const unsigned e_before = (unsigned)(iE / TBLK);
    const unsigned e_after  = (unsigned)((iE + EBLK) / TBLK);

    if (e_after == e_before) {
        // ---- bulk: 4 row-strided aligned float4 copies per thread ----
        const unsigned t = (i - e_before) * 256u + threadIdx.x;
        const unsigned k  = t % 180u;
        const unsigned rr = t / 180u;
        const unsigned r  = rr % 90u;          // rows r, r+90, r+180, r+270
        const unsigned bc = rr / 90u;

        const float* __restrict__ s0 = x + (size_t)(bc * 360u + r) * W + 4u * k;
        float* __restrict__ d0 =
            out + ((size_t)bc * Hp + (r + 3)) * Wp + 3 + 4u * k;

        f4a v0 = __builtin_nontemporal_load(reinterpret_cast<const f4a*>(s0));
        f4a v1 = __builtin_nontemporal_load(reinterpret_cast<const f4a*>(s0 + 90u * W));
        f4a v2 = __builtin_nontemporal_load(reinterpret_cast<const f4a*>(s0 + 180u * W));
        f4a v3 = __builtin_nontemporal_load(reinterpret_cast<const f4a*>(s0 + 270u * W));

        f4u a0; a0.x = v0.x; a0.y = v0.y; a0.z = v0.z; a0.w = v0.w;
        f4u a1; a1.x = v1.x; a1.y = v1.y; a1.z = v1.z; a1.w = v1.w;
        f4u a2; a2.x = v2.x; a2.y = v2.y; a2.z = v2.z; a2.w = v2.w;
        f4u a3; a3.x = v3.x; a3.y = v3.y; a3.z = v3.z; a3.w = v3.w;
        __builtin_nontemporal_store(a0, reinterpret_cast<f4u*>(d0));
        __builtin_nontemporal_store(a1, reinterpret_cast<f4u*>(d0 + 90u * Wp));
        __builtin_nontemporal_store(a2, reinterpret_cast<f4u*>(d0 + 180u * Wp));
        __builtin_nontemporal_store(a3, reinterpret_cast<f4u*>(d0 + 270u * Wp));
    } else {
        // ---- edges (identical to R9) ----
        const unsigned e = e_before * 256u + threadIdx.x;
        const unsigned bc = e / EPP;
        const unsigned q  = e % EPP;

        if (q < 2160u) {                       // middle-row edge columns
            const int r  = (int)(q / 6u);
            const int c6 = (int)(q % 6u);
            const int ho  = r + p;
            const int h   = r;
            const int col = (c6 < 3) ? c6 : (720 + c6);
            const int w   = (c6 < 3) ? (717 + c6) : (c6 - 3);
            out[((size_t)bc * Hp + ho) * Wp + col] =
                x[((size_t)bc * H + h) * W + w];
        } else {                               // halo rows, float2 groups
            const unsigned q2 = q - 2160u;     // [0, 2178)
            const unsigned g  = q2 % 363u;
            const int hr = (int)(q2 / 363u);   // 0..5
            const int ho = (hr < p) ? hr : (H + hr);
            const int h  = (hr < p) ? (p - 1 - hr) : (362 - hr);

            const float* __restrict__ srow = x + ((size_t)bc * H + h) * W;
            float* __restrict__ orow = out + ((size_t)bc * Hp + ho) * Wp;

            const int c0 = 2 * (int)g;
            int wr0 = c0 + 360; if (wr0 >= Wp) wr0 -= Wp;
            int wr1 = c0 + 361; if (wr1 >= Wp) wr1 -= Wp;
            int w0 = wr0 - p; if (w0 < 0) w0 += W; else if (w0 >= W) w0 -= W;
            int w1 = wr1 - p; if (w1 < 0) w1 += W; else if (w1 >= W) w1 -= W;

            f2u sv;
            if (w1 == w0 + 1) {
                sv = *reinterpret_cast<const f2u*>(srow + w0);
            } else {
                sv.x = srow[w0]; sv.y = srow[w1];
            }
            __builtin_nontemporal_store(sv, reinterpret_cast<f2u*>(orow + c0));
        }
    }
}

extern "C" void kernel_launch(void* const* d_in, const int* in_sizes, int n_in,
                              void* d_out, int out_size, void* d_ws, size_t ws_size,
                              hipStream_t stream) {
    const float* x = (const float*)d_in[0];
    float* out = (float*)d_out;

    // 24,300 bulk (4 float4/thread) + 6,507 edge = 30,807 blocks.
    geo_pad_kernel<<<30807u, 256, 0, stream>>>(x, out);
}